// Round 1
// baseline (99.226 us; speedup 1.0000x reference)
//
#include <hip/hip_runtime.h>

// Cubic Bezier spline evaluation.
// t: (N,) sorted fp32 in [0,1); ctrl: (S*2, 2) fp32; joint: (S+1, 2) fp32.
// out: (N, 2) fp32.
//
// Memory-bound: ~33.5 MB read (t) + ~67 MB write (out); coefficient tables
// (~160 KB) stay cache-resident and, since t is sorted, every wave's gathers
// hit the same couple of segments (near-broadcast).

__global__ __launch_bounds__(256) void spline_eval(
    const float4* __restrict__ t4,      // t viewed as float4, n4 elements
    const float4* __restrict__ ctrl4,   // (S,) : p1x,p1y,p2x,p2y per segment
    const float2* __restrict__ joint2,  // (S+1,)
    float4* __restrict__ out4,          // out viewed as float4, 2 per thread
    int n4, int n, float Sf, int Smax)  // Smax = S-1
{
    int i = blockIdx.x * blockDim.x + threadIdx.x;
    if (i >= n4) return;

    float4 tv = t4[i];
    float ts[4] = {tv.x, tv.y, tv.z, tv.w};
    float rx[4], ry[4];

#pragma unroll
    for (int j = 0; j < 4; ++j) {
        // parity with reference: jnp.minimum(t, 1.0-1e-10) -> fp32 min(t, 1.0f)
        float tt = fminf(ts[j], 1.0f);
        float u = Sf * tt;
        float segf = floorf(u);
        float lt = u - segf;
        int seg = (int)segf;
        if (seg > Smax) {          // reference's over-clamp (seg == S)
            seg = Smax;
            lt = 1.0f;
        }
        float2 p0 = joint2[seg];
        float2 p3 = joint2[seg + 1];
        float4 c  = ctrl4[seg];    // p1 = (c.x,c.y), p2 = (c.z,c.w)

        // power-basis coefficients (== BEZIER_M @ pts)
        float c1x = 3.0f * (c.x - p0.x);
        float c2x = 3.0f * (p0.x - 2.0f * c.x + c.z);
        float c3x = (p3.x - p0.x) + 3.0f * (c.x - c.z);
        float c1y = 3.0f * (c.y - p0.y);
        float c2y = 3.0f * (p0.y - 2.0f * c.y + c.w);
        float c3y = (p3.y - p0.y) + 3.0f * (c.y - c.w);

        rx[j] = fmaf(lt, fmaf(lt, fmaf(lt, c3x, c2x), c1x), p0.x);
        ry[j] = fmaf(lt, fmaf(lt, fmaf(lt, c3y, c2y), c1y), p0.y);
    }

    int base = 4 * i;               // first sample index of this thread
    if (base + 4 <= n) {
        out4[2 * i]     = make_float4(rx[0], ry[0], rx[1], ry[1]);
        out4[2 * i + 1] = make_float4(rx[2], ry[2], rx[3], ry[3]);
    } else {
        // tail (not hit for N = 8388608, kept for generality)
        float* out = reinterpret_cast<float*>(out4);
        for (int j = 0; j < 4 && base + j < n; ++j) {
            out[2 * (base + j)]     = rx[j];
            out[2 * (base + j) + 1] = ry[j];
        }
    }
}

extern "C" void kernel_launch(void* const* d_in, const int* in_sizes, int n_in,
                              void* d_out, int out_size, void* d_ws, size_t ws_size,
                              hipStream_t stream) {
    const float* t     = (const float*)d_in[0];
    const float* ctrl  = (const float*)d_in[1];  // (S*2, 2)
    const float* joint = (const float*)d_in[2];  // (S+1, 2)
    float* out = (float*)d_out;

    int n = in_sizes[0];
    int S = in_sizes[2] / 2 - 1;

    int n4 = (n + 3) / 4;
    int block = 256;
    int grid = (n4 + block - 1) / block;

    spline_eval<<<grid, block, 0, stream>>>(
        reinterpret_cast<const float4*>(t),
        reinterpret_cast<const float4*>(ctrl),
        reinterpret_cast<const float2*>(joint),
        reinterpret_cast<float4*>(out),
        n4, n, (float)S, S - 1);
}